// Round 11
// baseline (256.539 us; speedup 1.0000x reference)
//
#include <hip/hip_runtime.h>
#include <math.h>

#define N_ROWS 65536
#define Q 4096
#define E 64
#define CT 64                 // codes staged per tile-step
#define NSPLIT 4              // Q split into quarters
#define NTS_Q 16              // tile-steps per quarter (1024 codes)
#define MARGIN 0.5f
#define CAPH 4                // candidate cap per (row, quarter)
#define CAPR 8192             // max flagged rows on fast fallback path
#define FLAGBIT 0x40000000
#define KMASK 0xFFFFF000u

typedef short s8v __attribute__((ext_vector_type(8)));   // 8 bf16 (4 VGPRs)
typedef float f4v __attribute__((ext_vector_type(4)));   // 4 fp32 acc

static __device__ __forceinline__ unsigned umin_(unsigned a, unsigned b) {
  return __builtin_elementwise_min(a, b);   // v_min_u32
}
static __device__ __forceinline__ unsigned umax_(unsigned a, unsigned b) {
  return __builtin_elementwise_max(a, b);   // v_max_u32
}

// ---------- exact-arithmetic helpers (validated absmax=0 rounds 1-10) ---------
__device__ __forceinline__ float pairwise_sq_sum64(const float* v) {
#pragma clang fp contract(off)
  float r[8];
#pragma unroll
  for (int j = 0; j < 8; ++j) r[j] = v[j] * v[j];
#pragma unroll
  for (int i = 8; i < 64; i += 8) {
#pragma unroll
    for (int j = 0; j < 8; ++j) {
      float p = v[i + j] * v[i + j];
      r[j] = r[j] + p;
    }
  }
  return ((r[0] + r[1]) + (r[2] + r[3])) + ((r[4] + r[5]) + (r[6] + r[7]));
}

__device__ __forceinline__ void load_row64(const float* __restrict__ src,
                                           float* dst) {
  const float4* p = (const float4*)src;
#pragma unroll
  for (int k4 = 0; k4 < 16; ++k4) {
    const float4 t = p[k4];
    dst[4 * k4 + 0] = t.x;
    dst[4 * k4 + 1] = t.y;
    dst[4 * k4 + 2] = t.z;
    dst[4 * k4 + 3] = t.w;
  }
}

// exact distance, reference-bitwise: sequential fmaf k ascending,
// RN(hsq+wsq), fmaf(-2,...)
__device__ __forceinline__ float exact_dist(const float* hv, float hs,
                                            const float* __restrict__ w,
                                            float wsqc, int c) {
  const float* wr = w + (size_t)c * E;
  float dot = 0.f;
#pragma unroll
  for (int k = 0; k < E; ++k) dot = fmaf(wr[k], hv[k], dot);
  return fmaf(-2.f, dot, hs + wsqc);
}

__device__ __forceinline__ unsigned short bf16_rn(float f) {
  unsigned int u = __float_as_uint(f);
  u += 0x7FFFu + ((u >> 16) & 1u);
  return (unsigned short)(u >> 16);
}

// ---------- fused prep: blocks 0..15 -> w path (+wT), 16..271 -> x path ------
__global__ __launch_bounds__(256) void prep_kernel(
    const float* __restrict__ w, const float* __restrict__ x,
    float* __restrict__ wsq, float* __restrict__ hsq,
    short* __restrict__ whiS, float* __restrict__ wT,
    int* __restrict__ cntFlag, int* __restrict__ ovfCnt) {
  if (blockIdx.x < 16) {
    const int q = blockIdx.x * 256 + threadIdx.x;
    if (q == 0) *ovfCnt = 0;
    float v[E];
    load_row64(w + (size_t)q * E, v);
    wsq[q] = pairwise_sq_sum64(v);
#pragma unroll
    for (int k = 0; k < E; ++k) wT[(size_t)k * Q + q] = v[k];
    const int T = q >> 6, code_in = q & 63;
#pragma unroll
    for (int ch = 0; ch < 8; ++ch) {
      s8v hi;
#pragma unroll
      for (int j = 0; j < 8; ++j) hi[j] = (short)bf16_rn(v[ch * 8 + j]);
      const size_t base = (size_t)T * 4096 + ((size_t)(ch * 64 + code_in)) * 8;
      *(s8v*)&whiS[base] = hi;
    }
  } else {
    const int n = (blockIdx.x - 16) * 256 + threadIdx.x;
    float v[E];
    load_row64(x + (size_t)n * E, v);
    hsq[n] = pairwise_sq_sum64(v);
    // ws is re-poisoned each launch: must zero all 4 quarters' cntFlag
    cntFlag[n] = 0;
    cntFlag[N_ROWS + n] = 0;
    cntFlag[2 * N_ROWS + n] = 0;
    cntFlag[3 * N_ROWS + n] = 0;
  }
}

// ---------- main: 1-term bf16 MFMA screen, packed branchless top-2 -----------
// grid = 2048: block b -> rows [(b>>2)*128, +128), quarter h = b&3 (1024 codes)
__global__ __launch_bounds__(256, 4) void dist_kernel(
    const float* __restrict__ x, const short* __restrict__ whiS,
    const float* __restrict__ wsq, const float* __restrict__ hsq,
    int* __restrict__ cntFlag, int* __restrict__ lists) {
  __shared__ short BsHi[2][CT * 64];   // 2 x 8 KB (double-buffered)
  __shared__ float WsS[2][CT];

  const int tid = threadIdx.x;
  const int wv = tid >> 6;
  const int lane = tid & 63;
  const int n = lane & 15;
  const int quad = lane >> 4;
  const int h = blockIdx.x & 3;
  const int rowBase = (blockIdx.x >> 2) * 128;
  const int ts0 = h * NTS_Q;

  // ---- A-frags: a = bf16(-2x), built once ----
  s8v ahi[2][2];  // [rowtile][ks]
#pragma unroll
  for (int rt = 0; rt < 2; ++rt) {
#pragma unroll
    for (int ks = 0; ks < 2; ++ks) {
      const int gRow = rowBase + wv * 32 + rt * 16 + n;
      const float* xp = x + (size_t)gRow * E + ks * 32 + quad * 8;
      const float4 v0 = ((const float4*)xp)[0];
      const float4 v1 = ((const float4*)xp)[1];
      float vals[8] = {v0.x, v0.y, v0.z, v0.w, v1.x, v1.y, v1.z, v1.w};
      s8v hi;
#pragma unroll
      for (int j = 0; j < 8; ++j) hi[j] = (short)bf16_rn(-2.f * vals[j]);
      ahi[rt][ks] = hi;
    }
  }

  // hsq + 4.0 offset folded into C-init (keeps packed floats positive)
  float hsqv4[2][4];
#pragma unroll
  for (int rt = 0; rt < 2; ++rt)
#pragma unroll
    for (int r = 0; r < 4; ++r)
      hsqv4[rt][r] = hsq[rowBase + wv * 32 + rt * 16 + quad * 4 + r] + 4.0f;

  // branchless packed top-2 per (rowtile, r): key = (bits(d+4)&KMASK)|code
  unsigned int m0[2][4], m1[2][4];
#pragma unroll
  for (int rt = 0; rt < 2; ++rt)
#pragma unroll
    for (int r = 0; r < 4; ++r) {
      m0[rt][r] = 0xFFFFFFFFu;
      m1[rt][r] = 0xFFFFFFFFu;
    }

  // ---- prefetch ts0 into registers ----
  int4 pH0, pH1;
  float pW;
  {
    const int4* gh = (const int4*)(whiS + (size_t)ts0 * 4096);
    pH0 = gh[tid];
    pH1 = gh[tid + 256];
    pW = (tid < CT) ? wsq[ts0 * CT + tid] : 0.f;
  }

#pragma unroll 1
  for (int ts = ts0; ts < ts0 + NTS_Q; ++ts) {
    const int buf = ts & 1;
    ((int4*)&BsHi[buf][0])[tid] = pH0;
    ((int4*)&BsHi[buf][0])[tid + 256] = pH1;
    if (tid < CT) WsS[buf][tid] = pW;
    __syncthreads();  // single barrier per ts
    if (ts + 1 < ts0 + NTS_Q) {
      const int4* gh = (const int4*)(whiS + (size_t)(ts + 1) * 4096);
      pH0 = gh[tid];
      pH1 = gh[tid + 256];
      if (tid < CT) pW = wsq[(ts + 1) * CT + tid];
    }

#pragma unroll
    for (int ct = 0; ct < 4; ++ct) {
      const s8v bhi0 = *(const s8v*)&BsHi[buf][(size_t)((0 * 4 + quad) * 64 + ct * 16 + n) * 8];
      const s8v bhi1 = *(const s8v*)&BsHi[buf][(size_t)((1 * 4 + quad) * 64 + ct * 16 + n) * 8];
      const float wsn = WsS[buf][ct * 16 + n];
      const unsigned int codeT = (unsigned int)(ts * CT + ct * 16 + n);
#pragma unroll
      for (int rt = 0; rt < 2; ++rt) {
        f4v acc;
        acc[0] = hsqv4[rt][0] + wsn;
        acc[1] = hsqv4[rt][1] + wsn;
        acc[2] = hsqv4[rt][2] + wsn;
        acc[3] = hsqv4[rt][3] + wsn;
        acc = __builtin_amdgcn_mfma_f32_16x16x32_bf16(ahi[rt][0], bhi0, acc, 0, 0, 0);
        acc = __builtin_amdgcn_mfma_f32_16x16x32_bf16(ahi[rt][1], bhi1, acc, 0, 0, 0);
#pragma unroll
        for (int r = 0; r < 4; ++r) {
          const unsigned int key =
              (__float_as_uint(acc[r]) & KMASK) | codeT;     // v_and_or_b32
          const unsigned int a = umin_(m0[rt][r], key);
          const unsigned int b = umax_(m0[rt][r], key);
          m0[rt][r] = a;
          m1[rt][r] = umin_(m1[rt][r], b);
        }
      }
    }
  }

  // ---- candidate push (per-quarter lists); local thr >= global thr ----
#pragma unroll
  for (int rt = 0; rt < 2; ++rt) {
#pragma unroll
    for (int r = 0; r < 4; ++r) {
      unsigned int km = m0[rt][r];
#pragma unroll
      for (int off = 1; off < 16; off <<= 1)
        km = umin_(km, (unsigned)__shfl_xor((int)km, off, 64));
      const float thr = __uint_as_float(km & KMASK) + MARGIN;
      const int row = rowBase + wv * 32 + rt * 16 + quad * 4 + r;
      int* cf = &cntFlag[h * N_ROWS + row];
      int* lst = &lists[(size_t)(h * N_ROWS + row) * CAPH];
      const float f0 = __uint_as_float(m0[rt][r] & KMASK);
      const float f1 = __uint_as_float(m1[rt][r] & KMASK);
      if (f0 <= thr) {
        const int pos = atomicAdd(cf, 1) & 0xFFFF;
        if (pos < CAPH) lst[pos] = (int)(m0[rt][r] & 0xFFFu);
        else atomicOr(cf, FLAGBIT);
      }
      // top-2: if the lane's 2nd-best is in-margin, a dropped 3rd could be
      // too -> flag (fast exact fallback takes the row)
      if (f1 <= thr) atomicOr(cf, FLAGBIT);
    }
  }
}

// ---------- merge: combine 4 quarters, exact recheck (bitwise), gather -------
__global__ __launch_bounds__(256) void merge_kernel(
    const float* __restrict__ x, const float* __restrict__ w,
    const float* __restrict__ wsq, const float* __restrict__ hsq,
    const int* __restrict__ cntFlag, const int* __restrict__ lists,
    float* __restrict__ out, int* __restrict__ ovfCnt,
    int* __restrict__ ovfRows) {
  __shared__ int bestS[256];
  const int tid = threadIdx.x;
  const int rowBase = blockIdx.x * 256;
  const int row = rowBase + tid;

  int cfv[NSPLIT];
  int anyFlag = 0;
#pragma unroll
  for (int qd = 0; qd < NSPLIT; ++qd) {
    cfv[qd] = cntFlag[qd * N_ROWS + row];
    anyFlag |= cfv[qd];
  }
  if ((anyFlag & FLAGBIT) != 0) {
    bestS[tid] = -1;
    ovfRows[atomicAdd(ovfCnt, 1)] = row;
  } else {
    float hv[E];
    load_row64(x + (size_t)row * E, hv);
    const float hs = hsq[row];
    float bd = INFINITY;
    int bi = 0x7FFFFFFF;
#pragma unroll
    for (int qd = 0; qd < NSPLIT; ++qd) {
      const int cv = cfv[qd] & 0xFFFF;
      const int nc = cv < CAPH ? cv : CAPH;
      for (int i = 0; i < nc; ++i) {
        const int c = lists[(size_t)(qd * N_ROWS + row) * CAPH + i];
        const float d = exact_dist(hv, hs, w, wsq[c], c);
        if (d < bd || (d == bd && c < bi)) { bd = d; bi = c; }
      }
    }
    bestS[tid] = bi;
    out[(size_t)N_ROWS * E + row] = (float)bi;
  }
  __syncthreads();
  // gather: 16 passes x (16 rows x 16 threads), coalesced 256 B per row
#pragma unroll 1
  for (int g = 0; g < 16; ++g) {
    const int r = g * 16 + (tid >> 4);
    const int part = tid & 15;
    const int b = bestS[r];
    if (b >= 0) {
      *(float4*)(out + (size_t)(rowBase + r) * E + part * 4) =
          *(const float4*)(w + (size_t)b * E + part * 4);
    }
  }
}

// ---------- fallback scan: one wave per (row, 256-code part) ----------------
__global__ __launch_bounds__(256) void fallback_scan(
    const float* __restrict__ x, const float* __restrict__ wT,
    const float* __restrict__ wsq, const float* __restrict__ hsq,
    float* __restrict__ out, const float* __restrict__ w,
    const int* __restrict__ ovfCnt, const int* __restrict__ ovfRows,
    float* __restrict__ pd, int* __restrict__ pc) {
  const int novf = *ovfCnt;
  const int fastR = novf < CAPR ? novf : CAPR;
  const int lane = threadIdx.x & 63;
  const int gw = blockIdx.x * 4 + (threadIdx.x >> 6);  // 4096 waves
  const int items = fastR * 16;
  for (int j = gw; j < items; j += 4096) {
    const int row = __builtin_amdgcn_readfirstlane(ovfRows[j >> 4]);
    const int part = j & 15;
    const float* xr = x + (size_t)row * E;       // wave-uniform -> s_load
    const float hs = hsq[row];
    const float* wtp = wT + part * 256 + lane;
    float d0 = 0.f, d1 = 0.f, d2 = 0.f, d3 = 0.f;
#pragma unroll 8
    for (int k = 0; k < E; ++k) {
      const float xk = xr[k];
      d0 = fmaf(wtp[(size_t)k * Q], xk, d0);
      d1 = fmaf(wtp[(size_t)k * Q + 64], xk, d1);
      d2 = fmaf(wtp[(size_t)k * Q + 128], xk, d2);
      d3 = fmaf(wtp[(size_t)k * Q + 192], xk, d3);
    }
    float bd = INFINITY;
    int bi = 0x7FFFFFFF;
    {
      const int c = part * 256 + lane;
      const float d = fmaf(-2.f, d0, hs + wsq[c]);
      if (d < bd || (d == bd && c < bi)) { bd = d; bi = c; }
    }
    {
      const int c = part * 256 + 64 + lane;
      const float d = fmaf(-2.f, d1, hs + wsq[c]);
      if (d < bd || (d == bd && c < bi)) { bd = d; bi = c; }
    }
    {
      const int c = part * 256 + 128 + lane;
      const float d = fmaf(-2.f, d2, hs + wsq[c]);
      if (d < bd || (d == bd && c < bi)) { bd = d; bi = c; }
    }
    {
      const int c = part * 256 + 192 + lane;
      const float d = fmaf(-2.f, d3, hs + wsq[c]);
      if (d < bd || (d == bd && c < bi)) { bd = d; bi = c; }
    }
#pragma unroll
    for (int off = 1; off < 64; off <<= 1) {
      const float od = __shfl_xor(bd, off, 64);
      const int oi = __shfl_xor(bi, off, 64);
      if (od < bd || (od == bd && oi < bi)) { bd = od; bi = oi; }
    }
    if (lane == 0) { pd[j] = bd; pc[j] = bi; }
  }
  // pathological overflow (> CAPR flagged rows): whole-row waves
  for (int i = CAPR + gw; i < novf; i += 4096) {
    const int row = __builtin_amdgcn_readfirstlane(ovfRows[i]);
    const float* xr = x + (size_t)row * E;
    const float hs = hsq[row];
    float bd = INFINITY;
    int bi = 0x7FFFFFFF;
    for (int cc = 0; cc < 64; ++cc) {
      const int c = cc * 64 + lane;
      float dot = 0.f;
#pragma unroll 8
      for (int k = 0; k < E; ++k)
        dot = fmaf(wT[(size_t)k * Q + c], xr[k], dot);
      const float d = fmaf(-2.f, dot, hs + wsq[c]);
      if (d < bd || (d == bd && c < bi)) { bd = d; bi = c; }
    }
#pragma unroll
    for (int off = 1; off < 64; off <<= 1) {
      const float od = __shfl_xor(bd, off, 64);
      const int oi = __shfl_xor(bi, off, 64);
      if (od < bd || (od == bd && oi < bi)) { bd = od; bi = oi; }
    }
    if (lane == 0) out[(size_t)N_ROWS * E + row] = (float)bi;
    out[(size_t)row * E + lane] = w[(size_t)bi * E + lane];
  }
}

// ---------- fallback finalize: reduce 16 parts/row, write idx + gather -------
__global__ __launch_bounds__(256) void fallback_finalize(
    const float* __restrict__ w, float* __restrict__ out,
    const int* __restrict__ ovfCnt, const int* __restrict__ ovfRows,
    const float* __restrict__ pd, const int* __restrict__ pc) {
  __shared__ int bestS[16];
  const int novf0 = *ovfCnt;
  const int fastR = novf0 < CAPR ? novf0 : CAPR;
  const int tid = threadIdx.x;
#pragma unroll 1
  for (int base = blockIdx.x * 16; base < fastR; base += gridDim.x * 16) {
    const int i = base + (tid >> 4);
    const int part = tid & 15;
    if (i < fastR && part == 0) {
      float bd = INFINITY;
      int bi = 0x7FFFFFFF;
#pragma unroll 1
      for (int p = 0; p < 16; ++p) {
        const float d = pd[i * 16 + p];
        const int c = pc[i * 16 + p];
        if (d < bd || (d == bd && c < bi)) { bd = d; bi = c; }
      }
      bestS[tid >> 4] = bi;
      out[(size_t)N_ROWS * E + ovfRows[i]] = (float)bi;
    }
    __syncthreads();
    if (i < fastR) {
      const int row = ovfRows[i];
      const int b = bestS[tid >> 4];
      *(float4*)(out + (size_t)row * E + part * 4) =
          *(const float4*)(w + (size_t)b * E + part * 4);
    }
    __syncthreads();
  }
}

extern "C" void kernel_launch(void* const* d_in, const int* in_sizes, int n_in,
                              void* d_out, int out_size, void* d_ws,
                              size_t ws_size, hipStream_t stream) {
  const float* x = (const float*)d_in[0];
  const float* w = (const float*)d_in[1];
  float* out = (float*)d_out;

  // ws layout (~8 MB): wsq[4096] | hsq[65536] | whiS[262144] s16 | wT[262144]
  //   | cntFlag[4*N] | lists[4*N*CAPH] | ovfCnt[4] | ovfRows[N]
  //   | pd[CAPR*16] f32 | pc[CAPR*16] i32
  float* wsq = (float*)d_ws;
  float* hsq = wsq + Q;
  short* whiS = (short*)(hsq + N_ROWS);
  float* wT = (float*)(whiS + (size_t)Q * E);
  int* cntFlag = (int*)(wT + (size_t)Q * E);
  int* lists = cntFlag + NSPLIT * N_ROWS;
  int* ovfCnt = lists + (size_t)NSPLIT * N_ROWS * CAPH;
  int* ovfRows = ovfCnt + 4;
  float* pd = (float*)(ovfRows + N_ROWS);
  int* pc = (int*)(pd + (size_t)CAPR * 16);

  prep_kernel<<<272, 256, 0, stream>>>(w, x, wsq, hsq, whiS, wT, cntFlag,
                                       ovfCnt);
  dist_kernel<<<(N_ROWS / 128) * NSPLIT, 256, 0, stream>>>(x, whiS, wsq, hsq,
                                                           cntFlag, lists);
  merge_kernel<<<N_ROWS / 256, 256, 0, stream>>>(x, w, wsq, hsq, cntFlag, lists,
                                                 out, ovfCnt, ovfRows);
  fallback_scan<<<1024, 256, 0, stream>>>(x, wT, wsq, hsq, out, w, ovfCnt,
                                          ovfRows, pd, pc);
  fallback_finalize<<<256, 256, 0, stream>>>(w, out, ovfCnt, ovfRows, pd, pc);
}

// Round 12
// 189.882 us; speedup vs baseline: 1.3510x; 1.3510x over previous
//
#include <hip/hip_runtime.h>
#include <math.h>

#define N_ROWS 65536
#define Q 4096
#define E 64
#define CT 64                 // codes staged per tile-step
#define NSPLIT 4              // Q split into quarters
#define NTS_Q 16              // tile-steps per quarter (1024 codes)
#define MARGIN 0.5f
#define CAPH 4                // candidate cap per (row, quarter)
#define CAPR 8192             // max flagged rows on fast fallback path
#define FLAGBIT 0x40000000
#define KMASK 0xFFFFF000u

typedef short s8v __attribute__((ext_vector_type(8)));   // 8 bf16 (4 VGPRs)
typedef float f4v __attribute__((ext_vector_type(4)));   // 4 fp32 acc

static __device__ __forceinline__ unsigned umin_(unsigned a, unsigned b) {
  return __builtin_elementwise_min(a, b);   // v_min_u32
}
static __device__ __forceinline__ unsigned umax_(unsigned a, unsigned b) {
  return __builtin_elementwise_max(a, b);   // v_max_u32
}

// ---------- exact-arithmetic helpers (validated absmax=0 rounds 1-11) ---------
__device__ __forceinline__ float pairwise_sq_sum64(const float* v) {
#pragma clang fp contract(off)
  float r[8];
#pragma unroll
  for (int j = 0; j < 8; ++j) r[j] = v[j] * v[j];
#pragma unroll
  for (int i = 8; i < 64; i += 8) {
#pragma unroll
    for (int j = 0; j < 8; ++j) {
      float p = v[i + j] * v[i + j];
      r[j] = r[j] + p;
    }
  }
  return ((r[0] + r[1]) + (r[2] + r[3])) + ((r[4] + r[5]) + (r[6] + r[7]));
}

__device__ __forceinline__ void load_row64(const float* __restrict__ src,
                                           float* dst) {
  const float4* p = (const float4*)src;
#pragma unroll
  for (int k4 = 0; k4 < 16; ++k4) {
    const float4 t = p[k4];
    dst[4 * k4 + 0] = t.x;
    dst[4 * k4 + 1] = t.y;
    dst[4 * k4 + 2] = t.z;
    dst[4 * k4 + 3] = t.w;
  }
}

// exact distance, reference-bitwise: sequential fmaf k ascending,
// RN(hsq+wsq), fmaf(-2,...)
__device__ __forceinline__ float exact_dist(const float* hv, float hs,
                                            const float* __restrict__ w,
                                            float wsqc, int c) {
  const float* wr = w + (size_t)c * E;
  float dot = 0.f;
#pragma unroll
  for (int k = 0; k < E; ++k) dot = fmaf(wr[k], hv[k], dot);
  return fmaf(-2.f, dot, hs + wsqc);
}

__device__ __forceinline__ unsigned short bf16_rn(float f) {
  unsigned int u = __float_as_uint(f);
  u += 0x7FFFu + ((u >> 16) & 1u);
  return (unsigned short)(u >> 16);
}

// ---------- fused prep: blocks 0..15 -> w path (+wT), 16..271 -> x path ------
__global__ __launch_bounds__(256) void prep_kernel(
    const float* __restrict__ w, const float* __restrict__ x,
    float* __restrict__ wsq, float* __restrict__ hsq,
    short* __restrict__ whiS, float* __restrict__ wT,
    int* __restrict__ cntFlag, int* __restrict__ ovfCnt) {
  if (blockIdx.x < 16) {
    const int q = blockIdx.x * 256 + threadIdx.x;
    if (q == 0) *ovfCnt = 0;
    float v[E];
    load_row64(w + (size_t)q * E, v);
    wsq[q] = pairwise_sq_sum64(v);
#pragma unroll
    for (int k = 0; k < E; ++k) wT[(size_t)k * Q + q] = v[k];
    const int T = q >> 6, code_in = q & 63;
#pragma unroll
    for (int ch = 0; ch < 8; ++ch) {
      s8v hi;
#pragma unroll
      for (int j = 0; j < 8; ++j) hi[j] = (short)bf16_rn(v[ch * 8 + j]);
      const size_t base = (size_t)T * 4096 + ((size_t)(ch * 64 + code_in)) * 8;
      *(s8v*)&whiS[base] = hi;
    }
  } else {
    const int n = (blockIdx.x - 16) * 256 + threadIdx.x;
    float v[E];
    load_row64(x + (size_t)n * E, v);
    hsq[n] = pairwise_sq_sum64(v);
    // ws is re-poisoned each launch: must zero all 4 quarters' cntFlag
    cntFlag[n] = 0;
    cntFlag[N_ROWS + n] = 0;
    cntFlag[2 * N_ROWS + n] = 0;
    cntFlag[3 * N_ROWS + n] = 0;
  }
}

// ---------- main: 1-term bf16 MFMA screen, packed branchless top-3 -----------
// grid = 2048: block b -> rows [(b>>2)*128, +128), quarter h = b&3 (1024 codes)
__global__ __launch_bounds__(256, 4) void dist_kernel(
    const float* __restrict__ x, const short* __restrict__ whiS,
    const float* __restrict__ wsq, const float* __restrict__ hsq,
    int* __restrict__ cntFlag, int* __restrict__ lists) {
  __shared__ short BsHi[2][CT * 64];   // 2 x 8 KB (double-buffered)
  __shared__ float WsS[2][CT];

  const int tid = threadIdx.x;
  const int wv = tid >> 6;
  const int lane = tid & 63;
  const int n = lane & 15;
  const int quad = lane >> 4;
  const int h = blockIdx.x & 3;
  const int rowBase = (blockIdx.x >> 2) * 128;
  const int ts0 = h * NTS_Q;

  // ---- A-frags: a = bf16(-2x), built once ----
  s8v ahi[2][2];  // [rowtile][ks]
#pragma unroll
  for (int rt = 0; rt < 2; ++rt) {
#pragma unroll
    for (int ks = 0; ks < 2; ++ks) {
      const int gRow = rowBase + wv * 32 + rt * 16 + n;
      const float* xp = x + (size_t)gRow * E + ks * 32 + quad * 8;
      const float4 v0 = ((const float4*)xp)[0];
      const float4 v1 = ((const float4*)xp)[1];
      float vals[8] = {v0.x, v0.y, v0.z, v0.w, v1.x, v1.y, v1.z, v1.w};
      s8v hi;
#pragma unroll
      for (int j = 0; j < 8; ++j) hi[j] = (short)bf16_rn(-2.f * vals[j]);
      ahi[rt][ks] = hi;
    }
  }

  // hsq + 4.0 offset folded into C-init (keeps packed floats positive)
  float hsqv4[2][4];
#pragma unroll
  for (int rt = 0; rt < 2; ++rt)
#pragma unroll
    for (int r = 0; r < 4; ++r)
      hsqv4[rt][r] = hsq[rowBase + wv * 32 + rt * 16 + quad * 4 + r] + 4.0f;

  // branchless packed top-3 per (rowtile, r): key = (bits(d+4)&KMASK)|code
  unsigned int m0[2][4], m1[2][4], m2[2][4];
#pragma unroll
  for (int rt = 0; rt < 2; ++rt)
#pragma unroll
    for (int r = 0; r < 4; ++r) {
      m0[rt][r] = 0xFFFFFFFFu;
      m1[rt][r] = 0xFFFFFFFFu;
      m2[rt][r] = 0xFFFFFFFFu;
    }

  // ---- prefetch ts0 into registers ----
  int4 pH0, pH1;
  float pW;
  {
    const int4* gh = (const int4*)(whiS + (size_t)ts0 * 4096);
    pH0 = gh[tid];
    pH1 = gh[tid + 256];
    pW = (tid < CT) ? wsq[ts0 * CT + tid] : 0.f;
  }

#pragma unroll 1
  for (int ts = ts0; ts < ts0 + NTS_Q; ++ts) {
    const int buf = ts & 1;
    ((int4*)&BsHi[buf][0])[tid] = pH0;
    ((int4*)&BsHi[buf][0])[tid + 256] = pH1;
    if (tid < CT) WsS[buf][tid] = pW;
    __syncthreads();  // single barrier per ts
    if (ts + 1 < ts0 + NTS_Q) {
      const int4* gh = (const int4*)(whiS + (size_t)(ts + 1) * 4096);
      pH0 = gh[tid];
      pH1 = gh[tid + 256];
      if (tid < CT) pW = wsq[(ts + 1) * CT + tid];
    }

#pragma unroll
    for (int ct = 0; ct < 4; ++ct) {
      const s8v bhi0 = *(const s8v*)&BsHi[buf][(size_t)((0 * 4 + quad) * 64 + ct * 16 + n) * 8];
      const s8v bhi1 = *(const s8v*)&BsHi[buf][(size_t)((1 * 4 + quad) * 64 + ct * 16 + n) * 8];
      const float wsn = WsS[buf][ct * 16 + n];
      const unsigned int codeT = (unsigned int)(ts * CT + ct * 16 + n);
#pragma unroll
      for (int rt = 0; rt < 2; ++rt) {
        f4v acc;
        acc[0] = hsqv4[rt][0] + wsn;
        acc[1] = hsqv4[rt][1] + wsn;
        acc[2] = hsqv4[rt][2] + wsn;
        acc[3] = hsqv4[rt][3] + wsn;
        acc = __builtin_amdgcn_mfma_f32_16x16x32_bf16(ahi[rt][0], bhi0, acc, 0, 0, 0);
        acc = __builtin_amdgcn_mfma_f32_16x16x32_bf16(ahi[rt][1], bhi1, acc, 0, 0, 0);
#pragma unroll
        for (int r = 0; r < 4; ++r) {
          const unsigned int key =
              (__float_as_uint(acc[r]) & KMASK) | codeT;     // v_and_or_b32
          // branchless 3-deep insertion: keeps m0 <= m1 <= m2
          const unsigned int a = umin_(m0[rt][r], key);
          const unsigned int b = umax_(m0[rt][r], key);
          m0[rt][r] = a;
          const unsigned int c = umin_(m1[rt][r], b);
          const unsigned int d = umax_(m1[rt][r], b);
          m1[rt][r] = c;
          m2[rt][r] = umin_(m2[rt][r], d);
        }
      }
    }
  }

  // ---- candidate push (per-quarter lists); local thr >= global thr ----
#pragma unroll
  for (int rt = 0; rt < 2; ++rt) {
#pragma unroll
    for (int r = 0; r < 4; ++r) {
      unsigned int km = m0[rt][r];
#pragma unroll
      for (int off = 1; off < 16; off <<= 1)
        km = umin_(km, (unsigned)__shfl_xor((int)km, off, 64));
      const float thr = __uint_as_float(km & KMASK) + MARGIN;
      const int row = rowBase + wv * 32 + rt * 16 + quad * 4 + r;
      int* cf = &cntFlag[h * N_ROWS + row];
      int* lst = &lists[(size_t)(h * N_ROWS + row) * CAPH];
      const float f0 = __uint_as_float(m0[rt][r] & KMASK);
      const float f1 = __uint_as_float(m1[rt][r] & KMASK);
      const float f2 = __uint_as_float(m2[rt][r] & KMASK);
      if (f0 <= thr) {
        const int pos = atomicAdd(cf, 1) & 0xFFFF;
        if (pos < CAPH) lst[pos] = (int)(m0[rt][r] & 0xFFFu);
        else atomicOr(cf, FLAGBIT);
      }
      if (f1 <= thr) {
        const int pos = atomicAdd(cf, 1) & 0xFFFF;
        if (pos < CAPH) lst[pos] = (int)(m1[rt][r] & 0xFFFu);
        else atomicOr(cf, FLAGBIT);
      }
      // only if a lane's 3rd-best is also in-margin could a dropped 4th be
      // in-margin -> flag (fast exact fallback takes the row)
      if (f2 <= thr) atomicOr(cf, FLAGBIT);
    }
  }
}

// ---------- merge: combine 4 quarters, exact recheck (bitwise), gather -------
__global__ __launch_bounds__(256) void merge_kernel(
    const float* __restrict__ x, const float* __restrict__ w,
    const float* __restrict__ wsq, const float* __restrict__ hsq,
    const int* __restrict__ cntFlag, const int* __restrict__ lists,
    float* __restrict__ out, int* __restrict__ ovfCnt,
    int* __restrict__ ovfRows) {
  __shared__ int bestS[256];
  const int tid = threadIdx.x;
  const int rowBase = blockIdx.x * 256;
  const int row = rowBase + tid;

  int cfv[NSPLIT];
  int anyFlag = 0;
#pragma unroll
  for (int qd = 0; qd < NSPLIT; ++qd) {
    cfv[qd] = cntFlag[qd * N_ROWS + row];
    anyFlag |= cfv[qd];
  }
  if ((anyFlag & FLAGBIT) != 0) {
    bestS[tid] = -1;
    ovfRows[atomicAdd(ovfCnt, 1)] = row;
  } else {
    float hv[E];
    load_row64(x + (size_t)row * E, hv);
    const float hs = hsq[row];
    float bd = INFINITY;
    int bi = 0x7FFFFFFF;
#pragma unroll
    for (int qd = 0; qd < NSPLIT; ++qd) {
      const int cv = cfv[qd] & 0xFFFF;
      const int nc = cv < CAPH ? cv : CAPH;
      for (int i = 0; i < nc; ++i) {
        const int c = lists[(size_t)(qd * N_ROWS + row) * CAPH + i];
        const float d = exact_dist(hv, hs, w, wsq[c], c);
        if (d < bd || (d == bd && c < bi)) { bd = d; bi = c; }
      }
    }
    bestS[tid] = bi;
    out[(size_t)N_ROWS * E + row] = (float)bi;
  }
  __syncthreads();
  // gather: 16 passes x (16 rows x 16 threads), coalesced 256 B per row
#pragma unroll 1
  for (int g = 0; g < 16; ++g) {
    const int r = g * 16 + (tid >> 4);
    const int part = tid & 15;
    const int b = bestS[r];
    if (b >= 0) {
      *(float4*)(out + (size_t)(rowBase + r) * E + part * 4) =
          *(const float4*)(w + (size_t)b * E + part * 4);
    }
  }
}

// ---------- fallback scan: one wave per (row, 256-code part) ----------------
__global__ __launch_bounds__(256) void fallback_scan(
    const float* __restrict__ x, const float* __restrict__ wT,
    const float* __restrict__ wsq, const float* __restrict__ hsq,
    float* __restrict__ out, const float* __restrict__ w,
    const int* __restrict__ ovfCnt, const int* __restrict__ ovfRows,
    float* __restrict__ pd, int* __restrict__ pc) {
  const int novf = *ovfCnt;
  const int fastR = novf < CAPR ? novf : CAPR;
  const int lane = threadIdx.x & 63;
  const int gw = blockIdx.x * 4 + (threadIdx.x >> 6);  // 4096 waves
  const int items = fastR * 16;
  for (int j = gw; j < items; j += 4096) {
    const int row = __builtin_amdgcn_readfirstlane(ovfRows[j >> 4]);
    const int part = j & 15;
    const float* xr = x + (size_t)row * E;       // wave-uniform -> s_load
    const float hs = hsq[row];
    const float* wtp = wT + part * 256 + lane;
    float d0 = 0.f, d1 = 0.f, d2 = 0.f, d3 = 0.f;
#pragma unroll 8
    for (int k = 0; k < E; ++k) {
      const float xk = xr[k];
      d0 = fmaf(wtp[(size_t)k * Q], xk, d0);
      d1 = fmaf(wtp[(size_t)k * Q + 64], xk, d1);
      d2 = fmaf(wtp[(size_t)k * Q + 128], xk, d2);
      d3 = fmaf(wtp[(size_t)k * Q + 192], xk, d3);
    }
    float bd = INFINITY;
    int bi = 0x7FFFFFFF;
    {
      const int c = part * 256 + lane;
      const float d = fmaf(-2.f, d0, hs + wsq[c]);
      if (d < bd || (d == bd && c < bi)) { bd = d; bi = c; }
    }
    {
      const int c = part * 256 + 64 + lane;
      const float d = fmaf(-2.f, d1, hs + wsq[c]);
      if (d < bd || (d == bd && c < bi)) { bd = d; bi = c; }
    }
    {
      const int c = part * 256 + 128 + lane;
      const float d = fmaf(-2.f, d2, hs + wsq[c]);
      if (d < bd || (d == bd && c < bi)) { bd = d; bi = c; }
    }
    {
      const int c = part * 256 + 192 + lane;
      const float d = fmaf(-2.f, d3, hs + wsq[c]);
      if (d < bd || (d == bd && c < bi)) { bd = d; bi = c; }
    }
#pragma unroll
    for (int off = 1; off < 64; off <<= 1) {
      const float od = __shfl_xor(bd, off, 64);
      const int oi = __shfl_xor(bi, off, 64);
      if (od < bd || (od == bd && oi < bi)) { bd = od; bi = oi; }
    }
    if (lane == 0) { pd[j] = bd; pc[j] = bi; }
  }
  // pathological overflow (> CAPR flagged rows): whole-row waves
  for (int i = CAPR + gw; i < novf; i += 4096) {
    const int row = __builtin_amdgcn_readfirstlane(ovfRows[i]);
    const float* xr = x + (size_t)row * E;
    const float hs = hsq[row];
    float bd = INFINITY;
    int bi = 0x7FFFFFFF;
    for (int cc = 0; cc < 64; ++cc) {
      const int c = cc * 64 + lane;
      float dot = 0.f;
#pragma unroll 8
      for (int k = 0; k < E; ++k)
        dot = fmaf(wT[(size_t)k * Q + c], xr[k], dot);
      const float d = fmaf(-2.f, dot, hs + wsq[c]);
      if (d < bd || (d == bd && c < bi)) { bd = d; bi = c; }
    }
#pragma unroll
    for (int off = 1; off < 64; off <<= 1) {
      const float od = __shfl_xor(bd, off, 64);
      const int oi = __shfl_xor(bi, off, 64);
      if (od < bd || (od == bd && oi < bi)) { bd = od; bi = oi; }
    }
    if (lane == 0) out[(size_t)N_ROWS * E + row] = (float)bi;
    out[(size_t)row * E + lane] = w[(size_t)bi * E + lane];
  }
}

// ---------- fallback finalize: reduce 16 parts/row, write idx + gather -------
__global__ __launch_bounds__(256) void fallback_finalize(
    const float* __restrict__ w, float* __restrict__ out,
    const int* __restrict__ ovfCnt, const int* __restrict__ ovfRows,
    const float* __restrict__ pd, const int* __restrict__ pc) {
  __shared__ int bestS[16];
  const int novf0 = *ovfCnt;
  const int fastR = novf0 < CAPR ? novf0 : CAPR;
  const int tid = threadIdx.x;
#pragma unroll 1
  for (int base = blockIdx.x * 16; base < fastR; base += gridDim.x * 16) {
    const int i = base + (tid >> 4);
    const int part = tid & 15;
    if (i < fastR && part == 0) {
      float bd = INFINITY;
      int bi = 0x7FFFFFFF;
#pragma unroll 1
      for (int p = 0; p < 16; ++p) {
        const float d = pd[i * 16 + p];
        const int c = pc[i * 16 + p];
        if (d < bd || (d == bd && c < bi)) { bd = d; bi = c; }
      }
      bestS[tid >> 4] = bi;
      out[(size_t)N_ROWS * E + ovfRows[i]] = (float)bi;
    }
    __syncthreads();
    if (i < fastR) {
      const int row = ovfRows[i];
      const int b = bestS[tid >> 4];
      *(float4*)(out + (size_t)row * E + part * 4) =
          *(const float4*)(w + (size_t)b * E + part * 4);
    }
    __syncthreads();
  }
}

extern "C" void kernel_launch(void* const* d_in, const int* in_sizes, int n_in,
                              void* d_out, int out_size, void* d_ws,
                              size_t ws_size, hipStream_t stream) {
  const float* x = (const float*)d_in[0];
  const float* w = (const float*)d_in[1];
  float* out = (float*)d_out;

  // ws layout (~8 MB): wsq[4096] | hsq[65536] | whiS[262144] s16 | wT[262144]
  //   | cntFlag[4*N] | lists[4*N*CAPH] | ovfCnt[4] | ovfRows[N]
  //   | pd[CAPR*16] f32 | pc[CAPR*16] i32
  float* wsq = (float*)d_ws;
  float* hsq = wsq + Q;
  short* whiS = (short*)(hsq + N_ROWS);
  float* wT = (float*)(whiS + (size_t)Q * E);
  int* cntFlag = (int*)(wT + (size_t)Q * E);
  int* lists = cntFlag + NSPLIT * N_ROWS;
  int* ovfCnt = lists + (size_t)NSPLIT * N_ROWS * CAPH;
  int* ovfRows = ovfCnt + 4;
  float* pd = (float*)(ovfRows + N_ROWS);
  int* pc = (int*)(pd + (size_t)CAPR * 16);

  prep_kernel<<<272, 256, 0, stream>>>(w, x, wsq, hsq, whiS, wT, cntFlag,
                                       ovfCnt);
  dist_kernel<<<(N_ROWS / 128) * NSPLIT, 256, 0, stream>>>(x, whiS, wsq, hsq,
                                                           cntFlag, lists);
  merge_kernel<<<N_ROWS / 256, 256, 0, stream>>>(x, w, wsq, hsq, cntFlag, lists,
                                                 out, ovfCnt, ovfRows);
  fallback_scan<<<1024, 256, 0, stream>>>(x, wT, wsq, hsq, out, w, ovfCnt,
                                          ovfRows, pd, pc);
  fallback_finalize<<<256, 256, 0, stream>>>(w, out, ovfCnt, ovfRows, pd, pc);
}